// Round 8
// baseline (733.297 us; speedup 1.0000x reference)
//
#include <hip/hip_runtime.h>
#include <math.h>

// ---- static config ----
constexpr int cCIN = 21;
constexpr int cYH = 14, cYW = 22;
constexpr int NB = 256;   // persistent blocks (1 per CU -> guaranteed co-resident)
constexpr int BT = 256;   // threads per block (4 waves)

typedef __attribute__((ext_vector_type(8))) short bf16x8;
typedef __attribute__((ext_vector_type(4))) float f32x4;

__device__ inline unsigned short f2bf(float f) {
    union { float f; unsigned u; } v; v.f = f;
    unsigned u = v.u;
    unsigned r = (u + 0x7fffu + ((u >> 16) & 1u)) >> 16;
    return (unsigned short)r;
}

__device__ inline f32x4 mfma16(bf16x8 a, bf16x8 b, f32x4 c) {
    return __builtin_amdgcn_mfma_f32_16x16x32_bf16(a, b, c, 0, 0, 0);
}

// shared-memory union (max 32256 B)
struct SMem {
    union {
        float twL[8064];                        // P0: token_w transposed [c3][d]
        float pwL[576];                         // P1: patch weights [p][k]
        struct { float ppT[18][128]; float part[256]; float pooled[128]; } st; // stats
        unsigned short tr[4][32][72];           // gbwd: per-wave transpose tile
    };
};

// grid-wide barrier: per-phase counters, zeroed by k_zbar each call
__device__ inline void gbar(int* bar, int phase) {
    __syncthreads();
    if (threadIdx.x == 0) {
        __threadfence();
        __hip_atomic_fetch_add(&bar[phase], 1, __ATOMIC_RELEASE, __HIP_MEMORY_SCOPE_AGENT);
        while (__hip_atomic_load(&bar[phase], __ATOMIC_ACQUIRE, __HIP_MEMORY_SCOPE_AGENT) < NB) {
            __builtin_amdgcn_s_sleep(1);
        }
    }
    __syncthreads();
}

__global__ void k_zbar(int* bar) {
    if (threadIdx.x < 16) bar[threadIdx.x] = 0;
}

// ---------- stats: pool + pconv + BN/relu + tpool + alpha (one block per b) ----------
__device__ void stats_body(int b, int t, const float* __restrict__ x5,
        const float* __restrict__ pw, const float* __restrict__ pb,
        const float* __restrict__ g, const float* __restrict__ bb,
        const float* __restrict__ aw, float* __restrict__ alpha, SMem* s) {
    if (t < 128) { s->st.ppT[0][t] = 0.f; s->st.ppT[17][t] = 0.f; }
    #pragma unroll
    for (int i = 0; i < 8; ++i) {
        int ct = t + 256 * i;
        const float* p = x5 + b * 49152 + ct * 24;
        float ssum = 0.f;
        #pragma unroll
        for (int j = 0; j < 6; ++j) {
            f32x4 v = *(const f32x4*)(p + 4 * j);
            ssum += v[0] + v[1] + v[2] + v[3];
        }
        s->st.ppT[1 + (ct & 15)][ct >> 4] = ssum * (1.f / 24.f);
    }
    __syncthreads();
    int o = t >> 1, th = (t & 1) * 8;
    float acc[8];
    float pbo = pb[o];
    #pragma unroll
    for (int i = 0; i < 8; ++i) acc[i] = pbo;
    for (int c4 = 0; c4 < 32; ++c4) {
        union { f32x4 v[3]; float f[12]; } u;
        u.v[0] = *(const f32x4*)(pw + o * 384 + c4 * 12);
        u.v[1] = *(const f32x4*)(pw + o * 384 + c4 * 12 + 4);
        u.v[2] = *(const f32x4*)(pw + o * 384 + c4 * 12 + 8);
        f32x4 pv[10];
        #pragma unroll
        for (int r = 0; r < 10; ++r) pv[r] = *(f32x4*)&s->st.ppT[th + r][c4 * 4];
        #pragma unroll
        for (int cc = 0; cc < 4; ++cc) {
            float a0 = u.f[cc * 3], a1 = u.f[cc * 3 + 1], a2 = u.f[cc * 3 + 2];
            #pragma unroll
            for (int i = 0; i < 8; ++i)
                acc[i] += a0 * pv[i][cc] + a1 * pv[i + 1][cc] + a2 * pv[i + 2][cc];
        }
    }
    float scale = g[o] * rsqrtf(1.f + 1e-5f);
    float beta = bb[o];
    float partial = 0.f;
    #pragma unroll
    for (int i = 0; i < 8; ++i) {
        float v = acc[i] * scale + beta;
        partial += v > 0.f ? v : 0.f;
    }
    s->st.part[t] = partial;
    __syncthreads();
    if (t < 128) s->st.pooled[t] = (s->st.part[2 * t] + s->st.part[2 * t + 1]) * (1.f / 16.f);
    __syncthreads();
    if (t < 128) {
        float a = 1.f;
        for (int c4 = 0; c4 < 32; ++c4) {
            f32x4 av = *(const f32x4*)(aw + t * 128 + c4 * 4);
            f32x4 pv4 = *(f32x4*)&s->st.pooled[c4 * 4];
            a += av[0] * pv4[0] + av[1] * pv4[1] + av[2] * pv4[2] + av[3] * pv4[3];
        }
        alpha[b * 128 + t] = a;
    }
}

// ---------- conv-fwd GEMM unit (one wave) ----------
__device__ void gfwd_body(int wv, int l, const unsigned short* __restrict__ XT,
        const unsigned short* __restrict__ Wp, const float* __restrict__ alpha,
        unsigned short* __restrict__ Y0T) {
    int rm = wv >> 1, cn = wv & 1;
    int n = rm / 12, p0 = (rm % 12) * 32;
    int o0 = cn * 64;
    int sm = l & 15, skg = l >> 4;
    const unsigned short* XTn = XT + n * 57344;
    const unsigned short* WB = Wp + (o0 >> 4) * 512 + l * 8;
    f32x4 acc[2][4];
    #pragma unroll
    for (int mi = 0; mi < 2; ++mi)
        #pragma unroll
        for (int ni = 0; ni < 4; ++ni) acc[mi][ni] = (f32x4){0.f, 0.f, 0.f, 0.f};
    #pragma unroll
    for (int kt = 0; kt < 36; ++kt) {
        int a = kt >> 2;
        int off = (a / 3) * 24 + (a % 3);
        int kc = (kt & 3) * 32 + skg * 8;
        const unsigned short* ab = XTn + (p0 + sm + off) * 128 + kc;
        bf16x8 a0 = *(const bf16x8*)(ab);
        bf16x8 a1 = *(const bf16x8*)(ab + 2048);
        const unsigned short* wb = WB + kt * 4096;
        bf16x8 b0 = *(const bf16x8*)(wb);
        bf16x8 b1 = *(const bf16x8*)(wb + 512);
        bf16x8 b2 = *(const bf16x8*)(wb + 1024);
        bf16x8 b3 = *(const bf16x8*)(wb + 1536);
        acc[0][0] = mfma16(a0, b0, acc[0][0]);
        acc[0][1] = mfma16(a0, b1, acc[0][1]);
        acc[0][2] = mfma16(a0, b2, acc[0][2]);
        acc[0][3] = mfma16(a0, b3, acc[0][3]);
        acc[1][0] = mfma16(a1, b0, acc[1][0]);
        acc[1][1] = mfma16(a1, b1, acc[1][1]);
        acc[1][2] = mfma16(a1, b2, acc[1][2]);
        acc[1][3] = mfma16(a1, b3, acc[1][3]);
    }
    #pragma unroll
    for (int ni = 0; ni < 4; ++ni) {
        int o = o0 + ni * 16 + sm;
        float s = 0.f;
        #pragma unroll
        for (int bb2 = 0; bb2 < 16; ++bb2) { float a = alpha[bb2 * 128 + o]; s += a * a; }
        #pragma unroll
        for (int mi = 0; mi < 2; ++mi) {
            #pragma unroll
            for (int r = 0; r < 4; ++r) {
                int p = p0 + mi * 16 + skg * 4 + r;
                bool valid = ((p % 24) < cYW) && ((p / 24) < cYH);
                float v = valid ? acc[mi][ni][r] * s : 0.f;
                Y0T[n * 65536 + (64 + p) * 128 + o] = f2bf(v);
            }
        }
    }
}

// ---------- conv-bwd GEMM unit (one wave) + residual RMW + XT/xfM emit ----------
__device__ void gbwd_body(int wv, int l, int wslot, const unsigned short* __restrict__ Y0T,
        const unsigned short* __restrict__ Wpb, float* __restrict__ x5,
        unsigned short* __restrict__ xdst, int mode, SMem* s) {
    unsigned short (*tr)[72] = s->tr[wslot];   // wave-private: in-order DS pipe, no barrier
    int rm = wv >> 1, cn = wv & 1;
    int n = rm / 12, p0 = (rm % 12) * 32;
    int c0 = cn * 64;
    int sm = l & 15, skg = l >> 4;
    const unsigned short* Yn = Y0T + n * 65536 + 64 * 128;
    const unsigned short* WB = Wpb + (c0 >> 4) * 512 + l * 8;
    f32x4 acc[2][4];
    #pragma unroll
    for (int mi = 0; mi < 2; ++mi)
        #pragma unroll
        for (int ni = 0; ni < 4; ++ni) acc[mi][ni] = (f32x4){0.f, 0.f, 0.f, 0.f};
    #pragma unroll
    for (int kt = 0; kt < 36; ++kt) {
        int a = kt >> 2;
        int off = (a / 3) * 24 + (a % 3);
        int kc = (kt & 3) * 32 + skg * 8;
        const unsigned short* ab = Yn + (p0 + sm - off) * 128 + kc;
        bf16x8 a0 = *(const bf16x8*)(ab);
        bf16x8 a1 = *(const bf16x8*)(ab + 2048);
        const unsigned short* wb = WB + kt * 4096;
        bf16x8 b0 = *(const bf16x8*)(wb);
        bf16x8 b1 = *(const bf16x8*)(wb + 512);
        bf16x8 b2 = *(const bf16x8*)(wb + 1024);
        bf16x8 b3 = *(const bf16x8*)(wb + 1536);
        acc[0][0] = mfma16(a0, b0, acc[0][0]);
        acc[0][1] = mfma16(a0, b1, acc[0][1]);
        acc[0][2] = mfma16(a0, b2, acc[0][2]);
        acc[0][3] = mfma16(a0, b3, acc[0][3]);
        acc[1][0] = mfma16(a1, b0, acc[1][0]);
        acc[1][1] = mfma16(a1, b1, acc[1][1]);
        acc[1][2] = mfma16(a1, b2, acc[1][2]);
        acc[1][3] = mfma16(a1, b3, acc[1][3]);
    }
    #pragma unroll
    for (int ni = 0; ni < 4; ++ni) {
        int cl = ni * 16 + sm;
        int c = c0 + cl;
        #pragma unroll
        for (int mi = 0; mi < 2; ++mi) {
            int pl = mi * 16 + skg * 4;
            float* dst = x5 + n * 49152 + c * 384 + p0 + pl;
            f32x4 ov = *(f32x4*)dst;
            #pragma unroll
            for (int r = 0; r < 4; ++r) {
                ov[r] += acc[mi][ni][r];
                tr[pl + r][cl] = f2bf(ov[r]);
            }
            *(f32x4*)dst = ov;
        }
    }
    if (mode == 0) {
        #pragma unroll
        for (int pass = 0; pass < 4; ++pass) {
            int idx = pass * 64 + l;
            int row = idx >> 3, ch = idx & 7;
            *(bf16x8*)(xdst + n * 57344 + (p0 + row) * 128 + c0 + ch * 8) = *(bf16x8*)&tr[row][ch * 8];
        }
    } else {
        #pragma unroll
        for (int pass = 0; pass < 4; ++pass) {
            int idx = pass * 64 + l;
            int cl = idx >> 2, pl0 = (idx & 3) * 8;
            __attribute__((aligned(16))) unsigned short tmp[8];
            #pragma unroll
            for (int j2 = 0; j2 < 8; ++j2) tmp[j2] = tr[pl0 + j2][cl];
            *(bf16x8*)(xdst + n * 49152 + ((p0 >> 7) * 128 + c0 + cl) * 128 + (p0 & 127) + pl0) =
                *(bf16x8*)tmp;
        }
    }
}

// ---------- head GEMMs (one wave each) ----------
__device__ void gemmZ_body(int wv, int l, const unsigned short* __restrict__ xfM,
        const unsigned short* __restrict__ w2p, unsigned short* __restrict__ Zt) {
    int b = wv / 12, m0 = (wv % 12) * 32;
    int sm = l & 15, skg = l >> 4;
    f32x4 acc[2][2];
    #pragma unroll
    for (int mi = 0; mi < 2; ++mi)
        #pragma unroll
        for (int ni = 0; ni < 2; ++ni) acc[mi][ni] = (f32x4){0.f, 0.f, 0.f, 0.f};
    #pragma unroll
    for (int kt = 0; kt < 4; ++kt) {
        int kc = kt * 32 + skg * 8;
        const unsigned short* ab = xfM + b * 49152 + (m0 + sm) * 128 + kc;
        bf16x8 a0 = *(const bf16x8*)(ab);
        bf16x8 a1 = *(const bf16x8*)(ab + 2048);
        bf16x8 b0 = *(const bf16x8*)(w2p + sm * 128 + kc);
        bf16x8 b1 = *(const bf16x8*)(w2p + (16 + sm) * 128 + kc);
        acc[0][0] = mfma16(a0, b0, acc[0][0]);
        acc[0][1] = mfma16(a0, b1, acc[0][1]);
        acc[1][0] = mfma16(a1, b0, acc[1][0]);
        acc[1][1] = mfma16(a1, b1, acc[1][1]);
    }
    #pragma unroll
    for (int mi = 0; mi < 2; ++mi)
        #pragma unroll
        for (int ni = 0; ni < 2; ++ni) {
            int q = ni * 16 + sm;
            int mh = m0 + mi * 16 + skg * 4;
            #pragma unroll
            for (int r = 0; r < 4; ++r)
                Zt[b * 12288 + q * 384 + mh + r] = f2bf(acc[mi][ni][r]);
        }
}

__device__ void gemmO_body(int wv, int l, const unsigned short* __restrict__ w1p,
        const unsigned short* __restrict__ Zt, const float* __restrict__ b1,
        const float* __restrict__ w2s, const float* __restrict__ b2,
        float* __restrict__ out) {
    int b = wv / 3, p0 = (wv % 3) * 32;
    int sm = l & 15, skg = l >> 4;
    f32x4 acc[2][2];
    #pragma unroll
    for (int mi = 0; mi < 2; ++mi)
        #pragma unroll
        for (int ni = 0; ni < 2; ++ni) acc[mi][ni] = (f32x4){0.f, 0.f, 0.f, 0.f};
    #pragma unroll
    for (int kt = 0; kt < 12; ++kt) {
        int kc = kt * 32 + skg * 8;
        const unsigned short* ab = w1p + (p0 + sm) * 384 + kc;
        bf16x8 a0 = *(const bf16x8*)(ab);
        bf16x8 a1 = *(const bf16x8*)(ab + 16 * 384);
        const unsigned short* zb = Zt + b * 12288 + sm * 384 + kc;
        bf16x8 b0 = *(const bf16x8*)(zb);
        bf16x8 b1v = *(const bf16x8*)(zb + 16 * 384);
        acc[0][0] = mfma16(a0, b0, acc[0][0]);
        acc[0][1] = mfma16(a0, b1v, acc[0][1]);
        acc[1][0] = mfma16(a1, b0, acc[1][0]);
        acc[1][1] = mfma16(a1, b1v, acc[1][1]);
    }
    #pragma unroll
    for (int ni = 0; ni < 2; ++ni) {
        int q = ni * 16 + sm;
        if (q < 21) {
            float wsq = w2s[q], bq = b2[q];
            #pragma unroll
            for (int mi = 0; mi < 2; ++mi) {
                #pragma unroll
                for (int r = 0; r < 4; ++r) {
                    int p = p0 + mi * 16 + skg * 4 + r;
                    out[b * 2016 + p * 21 + q] = acc[mi][ni][r] + b1[p] * wsq + bq;
                }
            }
        }
    }
}

// ---------- the persistent kernel: whole network, 10 phases, 9 grid barriers ----------
__global__ __launch_bounds__(BT) void k_all(
        const float* __restrict__ x, const float* __restrict__ token_w,
        const float* __restrict__ patch_w, const float* __restrict__ patch_b,
        const float* __restrict__ Wi, const float* __restrict__ pconv_w,
        const float* __restrict__ pconv_b, const float* __restrict__ bn_g,
        const float* __restrict__ bn_b, const float* __restrict__ aconv_w,
        const float* __restrict__ fc1_w, const float* __restrict__ fc1_b,
        const float* __restrict__ fc2_w, const float* __restrict__ fc2_b,
        float* __restrict__ out,
        float* __restrict__ x5, float* __restrict__ alpha,
        unsigned short* __restrict__ Wp, unsigned short* __restrict__ w1p,
        unsigned short* __restrict__ w2p, float* __restrict__ w2s,
        float* __restrict__ emb, unsigned short* __restrict__ XT,
        unsigned short* __restrict__ Y0T, int* bar) {
    __shared__ SMem s;
    int t = threadIdx.x;
    int g = blockIdx.x * BT + t;
    int wv = g >> 6;           // global wave slot (0..1023)
    int l = t & 63;

    // stage token_w transposed into LDS (for coalesced emb reads in P0)
    for (int z = t; z < 8064; z += BT) {
        int d = z / 63, c3 = z % 63;
        s.twL[c3 * 128 + d] = token_w[z];
    }
    __syncthreads();

    // ---- P0: weight packs + embed + Y0T halo (grid-stride) ----
    for (int e0 = g; e0 < 1040416; e0 += NB * BT) {
        int e = e0;
        if (e < 589824) {
            int lyr = e / 294912;
            int rem = e % 294912;
            int dir = rem / 147456;
            int q = rem % 147456;
            int kt = q >> 12;
            int oi = (q >> 9) & 7;
            int kg = (q >> 7) & 3;
            int r  = (q >> 3) & 15;
            int j  = q & 7;
            int k = kt * 32 + kg * 8 + j;
            int a = k >> 7;
            int o, c;
            if (dir == 0) { o = oi * 16 + r; c = k & 127; }
            else          { o = k & 127;     c = oi * 16 + r; }
            Wp[e] = f2bf(Wi[lyr * 147456 + o * 1152 + c * 9 + a]);
            continue;
        }
        e -= 589824;
        if (e < 36864) {
            int p = e / 384, mh = e % 384;
            w1p[e] = f2bf(fc1_w[p * 384 + 3 * (mh & 127) + (mh >> 7)]);
            continue;
        }
        e -= 36864;
        if (e < 4096) {
            int q = e >> 7, d = e & 127;
            w2p[e] = (q < 21) ? f2bf(fc2_w[q * 128 + d]) : (unsigned short)0;
            continue;
        }
        e -= 4096;
        if (e < 32) {
            if (e < 21) {
                float ssum = 0.f;
                for (int d = 0; d < 128; ++d) ssum += fc2_w[e * 128 + d];
                w2s[e] = ssum;
            } else w2s[e] = 0.f;
            continue;
        }
        e -= 32;
        if (e < 393216) {
            int d = e & 127;
            int r = e >> 7;
            int ll = r % 192;
            int b = r / 192;
            int lm = (ll == 0) ? 191 : ll - 1;
            int lp = (ll == 191) ? 0 : ll + 1;
            const float* xb = x + b * 4032;
            int i2 = d >> 1;
            float dv = expf(-(float)(2 * i2) * (9.210340371976184f / 128.f));
            float ang = (float)ll * dv;
            float acc = (d & 1) ? cosf(ang) : sinf(ang);
            for (int c = 0; c < cCIN; ++c) {
                float x0 = xb[lm * 21 + c], x1 = xb[ll * 21 + c], x2 = xb[lp * 21 + c];
                acc += x0 * s.twL[(c * 3 + 0) * 128 + d]
                     + x1 * s.twL[(c * 3 + 1) * 128 + d]
                     + x2 * s.twL[(c * 3 + 2) * 128 + d];
            }
            emb[e] = acc;
            continue;
        }
        e -= 393216;
        {   // Y0T lower-halo zero (rows 0..63 per n)
            int n = e >> 10, j = e & 1023;
            bf16x8 z = {0, 0, 0, 0, 0, 0, 0, 0};
            *(bf16x8*)(Y0T + n * 65536 + j * 8) = z;
        }
    }
    gbar(bar, 0);

    // ---- P1: patch embed -> x5 (f32) + XT (bf16), zero XT rows 384..447 ----
    for (int z = t; z < 576; z += BT) ((float*)s.pwL)[z] = patch_w[z];
    __syncthreads();
    for (int u = g; u < 786432; u += NB * BT) {
        int pair = u / 24;
        int p = u % 24;
        int i = pair >> 4, tt = pair & 15;
        const float* ebase = emb + i * 192;
        int j0 = tt * 12;
        float acc = patch_b[p];
        #pragma unroll
        for (int k = 0; k < 24; ++k) {
            int j = j0 + k;
            j = j > 191 ? 191 : j;
            acc += ebase[j] * s.pwL[p * 24 + k];
        }
        int G = (i & 127) * 384 + tt * 24 + p;
        int b = i >> 7;
        int tp = G / 3072;
        int pp2 = (G % 3072) / 128;
        int cc = G & 127;
        int pp = tp * 24 + (pp2 & 1) * 12 + (pp2 >> 1);
        x5[b * 49152 + cc * 384 + pp] = acc;
        XT[b * 57344 + pp * 128 + cc] = f2bf(acc);
    }
    if (g < 16384) {
        int n = g >> 10, rem = g & 1023;
        int pp = 384 + (rem >> 4), c8 = (rem & 15) * 8;
        bf16x8 z = {0, 0, 0, 0, 0, 0, 0, 0};
        *(bf16x8*)(XT + n * 57344 + pp * 128 + c8) = z;
    }
    gbar(bar, 1);

    // ---- layer 0 ----
    if (blockIdx.x < 16)
        stats_body(blockIdx.x, t, x5, pconv_w, pconv_b, bn_g, bn_b, aconv_w, alpha, &s);
    gbar(bar, 2);
    if (wv < 384) gfwd_body(wv, l, XT, Wp, alpha, Y0T);
    gbar(bar, 3);
    if (wv < 384) gbwd_body(wv, l, t >> 6, Y0T, Wp + 147456, x5, XT, 0, &s);
    gbar(bar, 4);

    // ---- layer 1 ----
    if (blockIdx.x < 16)
        stats_body(blockIdx.x, t, x5, pconv_w + 49152, pconv_b + 128, bn_g + 128,
                   bn_b + 128, aconv_w + 16384, alpha, &s);
    gbar(bar, 5);
    if (wv < 384) gfwd_body(wv, l, XT, Wp + 294912, alpha, Y0T);
    gbar(bar, 6);
    if (wv < 384) gbwd_body(wv, l, t >> 6, Y0T, Wp + 442368, x5, XT /*xfM*/, 1, &s);
    gbar(bar, 7);

    // ---- head ----
    if (wv < 192) gemmZ_body(wv, l, XT /*xfM*/, w2p, Y0T /*Zt*/);
    gbar(bar, 8);
    if (wv < 48) gemmO_body(wv, l, w1p, Y0T /*Zt*/, fc1_b, w2s, fc2_b, out);
}

extern "C" void kernel_launch(void* const* d_in, const int* in_sizes, int n_in,
                              void* d_out, int out_size, void* d_ws, size_t ws_size,
                              hipStream_t stream) {
    const float* x       = (const float*)d_in[0];
    const float* token_w = (const float*)d_in[1];
    const float* patch_w = (const float*)d_in[2];
    const float* patch_b = (const float*)d_in[3];
    const float* Wi      = (const float*)d_in[4];
    const float* pconv_w = (const float*)d_in[5];
    const float* pconv_b = (const float*)d_in[6];
    const float* bn_g    = (const float*)d_in[7];
    const float* bn_b    = (const float*)d_in[8];
    const float* aconv_w = (const float*)d_in[9];
    const float* fc1_w   = (const float*)d_in[10];
    const float* fc1_b   = (const float*)d_in[11];
    const float* fc2_w   = (const float*)d_in[12];
    const float* fc2_b   = (const float*)d_in[13];
    float* out = (float*)d_out;

    // ---- workspace layout (float offsets), ~10.1 MB total ----
    float* ws    = (float*)d_ws;
    float* x5    = ws;                                        // 786432 f
    float* alpha = ws + 786432;                               // 2048 f
    unsigned short* Wp  = (unsigned short*)(ws + 788480);     // 589824 ush
    unsigned short* w1p = (unsigned short*)(ws + 1083392);    // 36864 ush
    unsigned short* w2p = (unsigned short*)(ws + 1101824);    // 4096 ush
    float* w2s   = ws + 1103872;                              // 32 f
    float* emb   = ws + 1136544;                              // 393216 f
    unsigned short* XT  = (unsigned short*)(ws + 1529760);    // 917504 ush (aliased xfM)
    unsigned short* Y0T = (unsigned short*)(ws + 1988512);    // 1048576 ush (aliased Zt)
    int* bar     = (int*)(ws + 2514944);                      // 16 ints

    k_zbar<<<1, 64, 0, stream>>>(bar);
    k_all<<<NB, BT, 0, stream>>>(x, token_w, patch_w, patch_b, Wi, pconv_w, pconv_b,
                                 bn_g, bn_b, aconv_w, fc1_w, fc1_b, fc2_w, fc2_b,
                                 out, x5, alpha, Wp, w1p, w2p, w2s, emb, XT, Y0T, bar);
}

// Round 12
// 220.900 us; speedup vs baseline: 3.3196x; 3.3196x over previous
//
#include <hip/hip_runtime.h>
#include <math.h>

// ---- static config ----
constexpr int cCIN = 21;
constexpr int cYH = 14, cYW = 22;

typedef __attribute__((ext_vector_type(8))) short bf16x8;
typedef __attribute__((ext_vector_type(4))) float f32x4;

__device__ inline unsigned short f2bf(float f) {
    union { float f; unsigned u; } v; v.f = f;
    unsigned u = v.u;
    unsigned r = (u + 0x7fffu + ((u >> 16) & 1u)) >> 16;
    return (unsigned short)r;
}

__device__ inline f32x4 mfma16(bf16x8 a, bf16x8 b, f32x4 c) {
    return __builtin_amdgcn_mfma_f32_16x16x32_bf16(a, b, c, 0, 0, 0);
}

// ---------- K0: fused one-time init (512 blocks) + embed->LDS->patch (256 blocks) ----------
// init items: Wp 589824 | w1p 36864 | w2p 4096 | w2s 32 | XThalo 16384 | Y0Thalo 16384 = 663584
__global__ __launch_bounds__(256) void k_initep(
        const float* __restrict__ x, const float* __restrict__ token_w,
        const float* __restrict__ patch_w, const float* __restrict__ patch_b,
        const float* __restrict__ Wi, const float* __restrict__ fc1_w,
        const float* __restrict__ fc2_w,
        float* __restrict__ x5, unsigned short* __restrict__ XT,
        unsigned short* __restrict__ Wp, unsigned short* __restrict__ w1p,
        unsigned short* __restrict__ w2p, float* __restrict__ w2s,
        unsigned short* __restrict__ Y0T) {
    __shared__ float twL[8064];    // token_w transposed [c3][d]
    __shared__ float embL[1536];   // 8 rows of the (2048,192) emb view
    __shared__ float pwL[576];
    int t = threadIdx.x;
    if (blockIdx.x < 256) {
        int blk = blockIdx.x;
        // stage token_w transposed: twL[c3*128+d]; bank-friendly (d = z&127 stride-1)
        for (int z = t; z < 8064; z += 256) {
            int d = z & 127, c3 = z >> 7;
            twL[z] = token_w[d * 63 + c3];
        }
        for (int z = t; z < 576; z += 256) pwL[z] = patch_w[z];
        __syncthreads();
        // ---- emb phase: flat f = blk*1536 + v over (b, ll, d) ----
        int b = blk >> 4;
        const float* xb = x + b * 4032;
        #pragma unroll
        for (int pass = 0; pass < 6; ++pass) {
            int v = t + pass * 256;
            int f = blk * 1536 + v;
            int ll = (f % 24576) / 128;
            int d = f & 127;
            int lm = (ll == 0) ? 191 : ll - 1;
            int lp = (ll == 191) ? 0 : ll + 1;
            int i2 = d >> 1;
            float dv = expf(-(float)(2 * i2) * (9.210340371976184f / 128.f));
            float ang = (float)ll * dv;
            float acc = (d & 1) ? cosf(ang) : sinf(ang);
            for (int c = 0; c < cCIN; ++c) {
                float x0 = xb[lm * 21 + c], x1 = xb[ll * 21 + c], x2 = xb[lp * 21 + c];
                acc += x0 * twL[(c * 3 + 0) * 128 + d]
                     + x1 * twL[(c * 3 + 1) * 128 + d]
                     + x2 * twL[(c * 3 + 2) * 128 + d];
            }
            embL[v] = acc;
        }
        __syncthreads();
        // ---- patch phase: rows i = blk*8 + ri ----
        #pragma unroll
        for (int pass = 0; pass < 12; ++pass) {
            int u = t + pass * 256;
            int ri = u / 384, rem = u % 384, tt = rem / 24, p = rem % 24;
            int i = blk * 8 + ri;
            int j0 = tt * 12;
            float acc = patch_b[p];
            #pragma unroll
            for (int k = 0; k < 24; ++k) {
                int j = j0 + k;
                j = j > 191 ? 191 : j;
                acc += embL[ri * 192 + j] * pwL[p * 24 + k];
            }
            int G = (i & 127) * 384 + tt * 24 + p;
            int b2 = i >> 7;
            int tp = G / 3072;
            int pp2 = (G % 3072) / 128;
            int cc = G & 127;
            int pp = tp * 24 + (pp2 & 1) * 12 + (pp2 >> 1);
            x5[b2 * 49152 + cc * 384 + pp] = acc;
            XT[b2 * 57344 + pp * 128 + cc] = f2bf(acc);
        }
        return;
    }
    // ---- init grid-stride (blocks 256..767) ----
    for (int e0 = (blockIdx.x - 256) * 256 + t; e0 < 663584; e0 += 512 * 256) {
        int e = e0;
        if (e < 589824) {
            int lyr = e / 294912;
            int rem = e % 294912;
            int dir = rem / 147456;
            int q = rem % 147456;
            int kt = q >> 12;
            int oi = (q >> 9) & 7;
            int kg = (q >> 7) & 3;
            int r  = (q >> 3) & 15;
            int j  = q & 7;
            int k = kt * 32 + kg * 8 + j;
            int a = k >> 7;
            int o, c;
            if (dir == 0) { o = oi * 16 + r; c = k & 127; }
            else          { o = k & 127;     c = oi * 16 + r; }
            Wp[e] = f2bf(Wi[lyr * 147456 + o * 1152 + c * 9 + a]);
            continue;
        }
        e -= 589824;
        if (e < 36864) {
            int p = e / 384, mh = e % 384;
            w1p[e] = f2bf(fc1_w[p * 384 + 3 * (mh & 127) + (mh >> 7)]);
            continue;
        }
        e -= 36864;
        if (e < 4096) {
            int q = e >> 7, d = e & 127;
            w2p[e] = (q < 21) ? f2bf(fc2_w[q * 128 + d]) : (unsigned short)0;
            continue;
        }
        e -= 4096;
        if (e < 32) {
            if (e < 21) {
                float ssum = 0.f;
                for (int d = 0; d < 128; ++d) ssum += fc2_w[e * 128 + d];
                w2s[e] = ssum;
            } else w2s[e] = 0.f;
            continue;
        }
        e -= 32;
        if (e < 16384) {   // XT replicate-halo rows 384..447 -> zero
            int n = e >> 10, rem2 = e & 1023;
            int pp = 384 + (rem2 >> 4), c8 = (rem2 & 15) * 8;
            bf16x8 z = {0, 0, 0, 0, 0, 0, 0, 0};
            *(bf16x8*)(XT + n * 57344 + pp * 128 + c8) = z;
            continue;
        }
        e -= 16384;
        {   // Y0T lower-halo rows 0..63 -> zero
            int n = e >> 10, j = e & 1023;
            bf16x8 z = {0, 0, 0, 0, 0, 0, 0, 0};
            *(bf16x8*)(Y0T + n * 65536 + j * 8) = z;
        }
    }
}

// ---------- K1: fused stats (pool+pconv+BN/relu+tpool+alpha), one block per b ----------
__global__ __launch_bounds__(256) void k_stats(const float* __restrict__ x5,
        const float* __restrict__ pw, const float* __restrict__ pb,
        const float* __restrict__ g, const float* __restrict__ bb,
        const float* __restrict__ aw, float* __restrict__ alpha) {
    __shared__ float ppT[18][128];
    __shared__ float part[256];
    __shared__ float pooled[128];
    int b = blockIdx.x, t = threadIdx.x;
    if (t < 128) { ppT[0][t] = 0.f; ppT[17][t] = 0.f; }
    #pragma unroll
    for (int i = 0; i < 8; ++i) {
        int ct = t + 256 * i;
        const float* p = x5 + b * 49152 + ct * 24;
        float ssum = 0.f;
        #pragma unroll
        for (int j = 0; j < 6; ++j) {
            f32x4 v = *(const f32x4*)(p + 4 * j);
            ssum += v[0] + v[1] + v[2] + v[3];
        }
        ppT[1 + (ct & 15)][ct >> 4] = ssum * (1.f / 24.f);
    }
    __syncthreads();
    int o = t >> 1, th = (t & 1) * 8;
    float acc[8];
    float pbo = pb[o];
    #pragma unroll
    for (int i = 0; i < 8; ++i) acc[i] = pbo;
    for (int c4 = 0; c4 < 32; ++c4) {
        union { f32x4 v[3]; float f[12]; } u;
        u.v[0] = *(const f32x4*)(pw + o * 384 + c4 * 12);
        u.v[1] = *(const f32x4*)(pw + o * 384 + c4 * 12 + 4);
        u.v[2] = *(const f32x4*)(pw + o * 384 + c4 * 12 + 8);
        f32x4 pv[10];
        #pragma unroll
        for (int r = 0; r < 10; ++r) pv[r] = *(f32x4*)&ppT[th + r][c4 * 4];
        #pragma unroll
        for (int cc = 0; cc < 4; ++cc) {
            float a0 = u.f[cc * 3], a1 = u.f[cc * 3 + 1], a2 = u.f[cc * 3 + 2];
            #pragma unroll
            for (int i = 0; i < 8; ++i)
                acc[i] += a0 * pv[i][cc] + a1 * pv[i + 1][cc] + a2 * pv[i + 2][cc];
        }
    }
    float scale = g[o] * rsqrtf(1.f + 1e-5f);
    float beta = bb[o];
    float partial = 0.f;
    #pragma unroll
    for (int i = 0; i < 8; ++i) {
        float v = acc[i] * scale + beta;
        partial += v > 0.f ? v : 0.f;
    }
    part[t] = partial;
    __syncthreads();
    if (t < 128) pooled[t] = (part[2 * t] + part[2 * t + 1]) * (1.f / 16.f);
    __syncthreads();
    if (t < 128) {
        float a = 1.f;
        for (int c4 = 0; c4 < 32; ++c4) {
            f32x4 av = *(const f32x4*)(aw + t * 128 + c4 * 4);
            f32x4 pv4 = *(f32x4*)&pooled[c4 * 4];
            a += av[0] * pv4[0] + av[1] * pv4[1] + av[2] * pv4[2] + av[3] * pv4[3];
        }
        alpha[b * 128 + t] = a;
    }
}

// ---------- K2: conv-fwd GEMM, 1-wave blocks, no barriers ----------
__global__ __launch_bounds__(64) void k_gfwd(const unsigned short* __restrict__ XT,
        const unsigned short* __restrict__ Wp, const float* __restrict__ alpha,
        unsigned short* __restrict__ Y0T) {
    int bid = blockIdx.x;
    int rm = bid >> 1, cn = bid & 1;
    int n = rm / 12, p0 = (rm % 12) * 32;
    int o0 = cn * 64;
    int l = threadIdx.x;
    int sm = l & 15, skg = l >> 4;
    const unsigned short* XTn = XT + n * 57344;
    const unsigned short* WB = Wp + (o0 >> 4) * 512 + l * 8;
    f32x4 acc[2][4];
    #pragma unroll
    for (int mi = 0; mi < 2; ++mi)
        #pragma unroll
        for (int ni = 0; ni < 4; ++ni) acc[mi][ni] = (f32x4){0.f, 0.f, 0.f, 0.f};
    #pragma unroll
    for (int kt = 0; kt < 36; ++kt) {
        int a = kt >> 2;
        int off = (a / 3) * 24 + (a % 3);
        int kc = (kt & 3) * 32 + skg * 8;
        const unsigned short* ab = XTn + (p0 + sm + off) * 128 + kc;
        bf16x8 a0 = *(const bf16x8*)(ab);
        bf16x8 a1 = *(const bf16x8*)(ab + 2048);
        const unsigned short* wb = WB + kt * 4096;
        bf16x8 b0 = *(const bf16x8*)(wb);
        bf16x8 b1 = *(const bf16x8*)(wb + 512);
        bf16x8 b2 = *(const bf16x8*)(wb + 1024);
        bf16x8 b3 = *(const bf16x8*)(wb + 1536);
        acc[0][0] = mfma16(a0, b0, acc[0][0]);
        acc[0][1] = mfma16(a0, b1, acc[0][1]);
        acc[0][2] = mfma16(a0, b2, acc[0][2]);
        acc[0][3] = mfma16(a0, b3, acc[0][3]);
        acc[1][0] = mfma16(a1, b0, acc[1][0]);
        acc[1][1] = mfma16(a1, b1, acc[1][1]);
        acc[1][2] = mfma16(a1, b2, acc[1][2]);
        acc[1][3] = mfma16(a1, b3, acc[1][3]);
    }
    #pragma unroll
    for (int ni = 0; ni < 4; ++ni) {
        int o = o0 + ni * 16 + sm;
        float s = 0.f;
        #pragma unroll
        for (int bb2 = 0; bb2 < 16; ++bb2) { float a = alpha[bb2 * 128 + o]; s += a * a; }
        #pragma unroll
        for (int mi = 0; mi < 2; ++mi) {
            #pragma unroll
            for (int r = 0; r < 4; ++r) {
                int p = p0 + mi * 16 + skg * 4 + r;
                bool valid = ((p % 24) < cYW) && ((p / 24) < cYH);
                float v = valid ? acc[mi][ni][r] * s : 0.f;
                Y0T[n * 65536 + (64 + p) * 128 + o] = f2bf(v);
            }
        }
    }
}

// ---------- K3: conv-bwd GEMM + residual RMW; emits XT (mode0) or xfM (mode1) ----------
__global__ __launch_bounds__(64) void k_gbwd(const unsigned short* __restrict__ Y0T,
        const unsigned short* __restrict__ Wpb, float* __restrict__ x5,
        unsigned short* __restrict__ xdst, int mode) {
    __shared__ unsigned short tr[32][72];
    int bid = blockIdx.x;
    int rm = bid >> 1, cn = bid & 1;
    int n = rm / 12, p0 = (rm % 12) * 32;
    int c0 = cn * 64;
    int l = threadIdx.x;
    int sm = l & 15, skg = l >> 4;
    const unsigned short* Yn = Y0T + n * 65536 + 64 * 128;
    const unsigned short* WB = Wpb + (c0 >> 4) * 512 + l * 8;
    f32x4 acc[2][4];
    #pragma unroll
    for (int mi = 0; mi < 2; ++mi)
        #pragma unroll
        for (int ni = 0; ni < 4; ++ni) acc[mi][ni] = (f32x4){0.f, 0.f, 0.f, 0.f};
    #pragma unroll
    for (int kt = 0; kt < 36; ++kt) {
        int a = kt >> 2;
        int off = (a / 3) * 24 + (a % 3);
        int kc = (kt & 3) * 32 + skg * 8;
        const unsigned short* ab = Yn + (p0 + sm - off) * 128 + kc;
        bf16x8 a0 = *(const bf16x8*)(ab);
        bf16x8 a1 = *(const bf16x8*)(ab + 2048);
        const unsigned short* wb = WB + kt * 4096;
        bf16x8 b0 = *(const bf16x8*)(wb);
        bf16x8 b1 = *(const bf16x8*)(wb + 512);
        bf16x8 b2 = *(const bf16x8*)(wb + 1024);
        bf16x8 b3 = *(const bf16x8*)(wb + 1536);
        acc[0][0] = mfma16(a0, b0, acc[0][0]);
        acc[0][1] = mfma16(a0, b1, acc[0][1]);
        acc[0][2] = mfma16(a0, b2, acc[0][2]);
        acc[0][3] = mfma16(a0, b3, acc[0][3]);
        acc[1][0] = mfma16(a1, b0, acc[1][0]);
        acc[1][1] = mfma16(a1, b1, acc[1][1]);
        acc[1][2] = mfma16(a1, b2, acc[1][2]);
        acc[1][3] = mfma16(a1, b3, acc[1][3]);
    }
    #pragma unroll
    for (int ni = 0; ni < 4; ++ni) {
        int cl = ni * 16 + sm;
        int c = c0 + cl;
        #pragma unroll
        for (int mi = 0; mi < 2; ++mi) {
            int pl = mi * 16 + skg * 4;
            float* dst = x5 + n * 49152 + c * 384 + p0 + pl;
            f32x4 ov = *(f32x4*)dst;
            #pragma unroll
            for (int r = 0; r < 4; ++r) {
                ov[r] += acc[mi][ni][r];
                tr[pl + r][cl] = f2bf(ov[r]);
            }
            *(f32x4*)dst = ov;
        }
    }
    __syncthreads();
    if (mode == 0) {
        #pragma unroll
        for (int pass = 0; pass < 4; ++pass) {
            int idx = pass * 64 + l;
            int row = idx >> 3, ch = idx & 7;
            *(bf16x8*)(xdst + n * 57344 + (p0 + row) * 128 + c0 + ch * 8) = *(bf16x8*)&tr[row][ch * 8];
        }
    } else {
        #pragma unroll
        for (int pass = 0; pass < 4; ++pass) {
            int idx = pass * 64 + l;
            int cl = idx >> 2, pl0 = (idx & 3) * 8;
            __attribute__((aligned(16))) unsigned short tmp[8];
            #pragma unroll
            for (int j2 = 0; j2 < 8; ++j2) tmp[j2] = tr[pl0 + j2][cl];
            *(bf16x8*)(xdst + n * 49152 + ((p0 >> 7) * 128 + c0 + cl) * 128 + (p0 & 127) + pl0) =
                *(bf16x8*)tmp;
        }
    }
}

// ---------- K4: fused head, one block per b: Zt in LDS, then out ----------
__global__ __launch_bounds__(256) void k_head(const unsigned short* __restrict__ xfM,
        const unsigned short* __restrict__ w2p, const unsigned short* __restrict__ w1p,
        const float* __restrict__ b1, const float* __restrict__ w2s,
        const float* __restrict__ b2, float* __restrict__ out) {
    __shared__ unsigned short ZtL[12288];   // [q 32][mh 384]
    int b = blockIdx.x, t = threadIdx.x;
    int w = t >> 6, l = t & 63;
    int sm = l & 15, skg = l >> 4;
    // phase Z: Zt[q][mh] = sum_d xfM[b][mh][d] * w2p[q][d]
    for (int zu = w; zu < 12; zu += 4) {
        int m0 = zu * 32;
        f32x4 acc[2][2];
        #pragma unroll
        for (int mi = 0; mi < 2; ++mi)
            #pragma unroll
            for (int ni = 0; ni < 2; ++ni) acc[mi][ni] = (f32x4){0.f, 0.f, 0.f, 0.f};
        #pragma unroll
        for (int kt = 0; kt < 4; ++kt) {
            int kc = kt * 32 + skg * 8;
            const unsigned short* ab = xfM + b * 49152 + (m0 + sm) * 128 + kc;
            bf16x8 a0 = *(const bf16x8*)(ab);
            bf16x8 a1 = *(const bf16x8*)(ab + 2048);
            bf16x8 b0 = *(const bf16x8*)(w2p + sm * 128 + kc);
            bf16x8 b1 = *(const bf16x8*)(w2p + (16 + sm) * 128 + kc);
            acc[0][0] = mfma16(a0, b0, acc[0][0]);
            acc[0][1] = mfma16(a0, b1, acc[0][1]);
            acc[1][0] = mfma16(a1, b0, acc[1][0]);
            acc[1][1] = mfma16(a1, b1, acc[1][1]);
        }
        #pragma unroll
        for (int mi = 0; mi < 2; ++mi)
            #pragma unroll
            for (int ni = 0; ni < 2; ++ni) {
                int q = ni * 16 + sm;
                int mh = m0 + mi * 16 + skg * 4;
                #pragma unroll
                for (int r = 0; r < 4; ++r)
                    ZtL[q * 384 + mh + r] = f2bf(acc[mi][ni][r]);
            }
    }
    __syncthreads();
    // phase O: out[b][p][q] = sum_mh w1p[p][mh]*Zt[q][mh] + b1[p]*w2s[q] + b2[q]
    if (w < 3) {
        int p0 = w * 32;
        f32x4 acc[2][2];
        #pragma unroll
        for (int mi = 0; mi < 2; ++mi)
            #pragma unroll
            for (int ni = 0; ni < 2; ++ni) acc[mi][ni] = (f32x4){0.f, 0.f, 0.f, 0.f};
        #pragma unroll
        for (int kt = 0; kt < 12; ++kt) {
            int kc = kt * 32 + skg * 8;
            const unsigned short* ab = w1p + (p0 + sm) * 384 + kc;
            bf16x8 a0 = *(const bf16x8*)(ab);
            bf16x8 a1 = *(const bf16x8*)(ab + 16 * 384);
            bf16x8 b0 = *(const bf16x8*)(&ZtL[sm * 384 + kc]);
            bf16x8 b1v = *(const bf16x8*)(&ZtL[(16 + sm) * 384 + kc]);
            acc[0][0] = mfma16(a0, b0, acc[0][0]);
            acc[0][1] = mfma16(a0, b1v, acc[0][1]);
            acc[1][0] = mfma16(a1, b0, acc[1][0]);
            acc[1][1] = mfma16(a1, b1v, acc[1][1]);
        }
        #pragma unroll
        for (int ni = 0; ni < 2; ++ni) {
            int q = ni * 16 + sm;
            if (q < 21) {
                float wsq = w2s[q], bq = b2[q];
                #pragma unroll
                for (int mi = 0; mi < 2; ++mi) {
                    #pragma unroll
                    for (int r = 0; r < 4; ++r) {
                        int p = p0 + mi * 16 + skg * 4 + r;
                        out[b * 2016 + p * 21 + q] = acc[mi][ni][r] + b1[p] * wsq + bq;
                    }
                }
            }
        }
    }
}

extern "C" void kernel_launch(void* const* d_in, const int* in_sizes, int n_in,
                              void* d_out, int out_size, void* d_ws, size_t ws_size,
                              hipStream_t stream) {
    const float* x       = (const float*)d_in[0];
    const float* token_w = (const float*)d_in[1];
    const float* patch_w = (const float*)d_in[2];
    const float* patch_b = (const float*)d_in[3];
    const float* Wi      = (const float*)d_in[4];
    const float* pconv_w = (const float*)d_in[5];
    const float* pconv_b = (const float*)d_in[6];
    const float* bn_g    = (const float*)d_in[7];
    const float* bn_b    = (const float*)d_in[8];
    const float* aconv_w = (const float*)d_in[9];
    const float* fc1_w   = (const float*)d_in[10];
    const float* fc1_b   = (const float*)d_in[11];
    const float* fc2_w   = (const float*)d_in[12];
    const float* fc2_b   = (const float*)d_in[13];
    float* out = (float*)d_out;

    // ---- workspace layout (float offsets) ----
    float* ws    = (float*)d_ws;
    float* x5    = ws;                                        // 786432 f
    float* alpha = ws + 786432;                               // 2048 f
    unsigned short* Wp  = (unsigned short*)(ws + 788480);     // 589824 ush
    unsigned short* w1p = (unsigned short*)(ws + 1083392);    // 36864 ush
    unsigned short* w2p = (unsigned short*)(ws + 1101824);    // 4096 ush
    float* w2s   = ws + 1103872;                              // 32 f
    unsigned short* XT  = (unsigned short*)(ws + 1103904);    // 917504 ush (alias xfM)
    unsigned short* Y0T = (unsigned short*)(ws + 1562656);    // 1048576 ush (alias Zt)

    k_initep<<<768, 256, 0, stream>>>(x, token_w, patch_w, patch_b, Wi, fc1_w, fc2_w,
                                      x5, XT, Wp, w1p, w2p, w2s, Y0T);
    // layer 0
    k_stats<<<16, 256, 0, stream>>>(x5, pconv_w, pconv_b, bn_g, bn_b, aconv_w, alpha);
    k_gfwd<<<384, 64, 0, stream>>>(XT, Wp, alpha, Y0T);
    k_gbwd<<<384, 64, 0, stream>>>(Y0T, Wp + 147456, x5, XT, 0);
    // layer 1
    k_stats<<<16, 256, 0, stream>>>(x5, pconv_w + 49152, pconv_b + 128, bn_g + 128,
                                    bn_b + 128, aconv_w + 16384, alpha);
    k_gfwd<<<384, 64, 0, stream>>>(XT, Wp + 294912, alpha, Y0T);
    k_gbwd<<<384, 64, 0, stream>>>(Y0T, Wp + 442368, x5, XT /*xfM*/, 1);
    // head
    k_head<<<16, 256, 0, stream>>>(XT /*xfM*/, w2p, w1p, fc1_b, w2s, fc2_b, out);
}

// Round 14
// 202.580 us; speedup vs baseline: 3.6198x; 1.0904x over previous
//
#include <hip/hip_runtime.h>
#include <math.h>

// ---- static config ----
constexpr int cCIN = 21;
constexpr int cYH = 14, cYW = 22;

typedef __attribute__((ext_vector_type(8))) short bf16x8;
typedef __attribute__((ext_vector_type(4))) float f32x4;

__device__ inline unsigned short f2bf(float f) {
    union { float f; unsigned u; } v; v.f = f;
    unsigned u = v.u;
    unsigned r = (u + 0x7fffu + ((u >> 16) & 1u)) >> 16;
    return (unsigned short)r;
}

__device__ inline f32x4 mfma16(bf16x8 a, bf16x8 b, f32x4 c) {
    return __builtin_amdgcn_mfma_f32_16x16x32_bf16(a, b, c, 0, 0, 0);
}

// ---------- K0: fused one-time init (512 blocks) + embed->LDS->patch (256 blocks) ----------
// init items: Wp 589824 | w1p 36864 | w2p 4096 | w2s 32 | XThalo 16384 | Y0Thalo 16384 = 663584
__global__ __launch_bounds__(256) void k_initep(
        const float* __restrict__ x, const float* __restrict__ token_w,
        const float* __restrict__ patch_w, const float* __restrict__ patch_b,
        const float* __restrict__ Wi, const float* __restrict__ fc1_w,
        const float* __restrict__ fc2_w,
        float* __restrict__ x5, unsigned short* __restrict__ XT,
        unsigned short* __restrict__ Wp, unsigned short* __restrict__ w1p,
        unsigned short* __restrict__ w2p, float* __restrict__ w2s,
        unsigned short* __restrict__ Y0T) {
    __shared__ float twL[8064];    // token_w transposed [c3][d]
    __shared__ float embL[1536];   // 8 rows of the (2048,192) emb view
    __shared__ float pwL[576];
    int t = threadIdx.x;
    if (blockIdx.x < 256) {
        int blk = blockIdx.x;
        for (int z = t; z < 8064; z += 256) {
            int d = z & 127, c3 = z >> 7;
            twL[z] = token_w[d * 63 + c3];
        }
        for (int z = t; z < 576; z += 256) pwL[z] = patch_w[z];
        __syncthreads();
        // ---- emb phase ----
        int b = blk >> 4;
        const float* xb = x + b * 4032;
        #pragma unroll
        for (int pass = 0; pass < 6; ++pass) {
            int v = t + pass * 256;
            int f = blk * 1536 + v;
            int ll = (f % 24576) / 128;
            int d = f & 127;
            int lm = (ll == 0) ? 191 : ll - 1;
            int lp = (ll == 191) ? 0 : ll + 1;
            int i2 = d >> 1;
            float dv = expf(-(float)(2 * i2) * (9.210340371976184f / 128.f));
            float ang = (float)ll * dv;
            float acc = (d & 1) ? cosf(ang) : sinf(ang);
            for (int c = 0; c < cCIN; ++c) {
                float x0 = xb[lm * 21 + c], x1 = xb[ll * 21 + c], x2 = xb[lp * 21 + c];
                acc += x0 * twL[(c * 3 + 0) * 128 + d]
                     + x1 * twL[(c * 3 + 1) * 128 + d]
                     + x2 * twL[(c * 3 + 2) * 128 + d];
            }
            embL[v] = acc;
        }
        __syncthreads();
        // ---- patch phase ----
        #pragma unroll
        for (int pass = 0; pass < 12; ++pass) {
            int u = t + pass * 256;
            int ri = u / 384, rem = u % 384, tt = rem / 24, p = rem % 24;
            int i = blk * 8 + ri;
            int j0 = tt * 12;
            float acc = patch_b[p];
            #pragma unroll
            for (int k = 0; k < 24; ++k) {
                int j = j0 + k;
                j = j > 191 ? 191 : j;
                acc += embL[ri * 192 + j] * pwL[p * 24 + k];
            }
            int G = (i & 127) * 384 + tt * 24 + p;
            int b2 = i >> 7;
            int tp = G / 3072;
            int pp2 = (G % 3072) / 128;
            int cc = G & 127;
            int pp = tp * 24 + (pp2 & 1) * 12 + (pp2 >> 1);
            x5[b2 * 49152 + cc * 384 + pp] = acc;
            XT[b2 * 57344 + pp * 128 + cc] = f2bf(acc);
        }
        return;
    }
    // ---- init grid-stride (blocks 256..767) ----
    for (int e0 = (blockIdx.x - 256) * 256 + t; e0 < 663584; e0 += 512 * 256) {
        int e = e0;
        if (e < 589824) {
            int lyr = e / 294912;
            int rem = e % 294912;
            int dir = rem / 147456;
            int q = rem % 147456;
            int kt = q >> 12;
            int oi = (q >> 9) & 7;
            int kg = (q >> 7) & 3;
            int r  = (q >> 3) & 15;
            int j  = q & 7;
            int k = kt * 32 + kg * 8 + j;
            int a = k >> 7;
            int o, c;
            if (dir == 0) { o = oi * 16 + r; c = k & 127; }
            else          { o = k & 127;     c = oi * 16 + r; }
            Wp[e] = f2bf(Wi[lyr * 147456 + o * 1152 + c * 9 + a]);
            continue;
        }
        e -= 589824;
        if (e < 36864) {
            int p = e / 384, mh = e % 384;
            w1p[e] = f2bf(fc1_w[p * 384 + 3 * (mh & 127) + (mh >> 7)]);
            continue;
        }
        e -= 36864;
        if (e < 4096) {
            int q = e >> 7, d = e & 127;
            w2p[e] = (q < 21) ? f2bf(fc2_w[q * 128 + d]) : (unsigned short)0;
            continue;
        }
        e -= 4096;
        if (e < 32) {
            if (e < 21) {
                float ssum = 0.f;
                for (int d = 0; d < 128; ++d) ssum += fc2_w[e * 128 + d];
                w2s[e] = ssum;
            } else w2s[e] = 0.f;
            continue;
        }
        e -= 32;
        if (e < 16384) {   // XT replicate-halo rows 384..447 -> zero
            int n = e >> 10, rem2 = e & 1023;
            int pp = 384 + (rem2 >> 4), c8 = (rem2 & 15) * 8;
            bf16x8 z = {0, 0, 0, 0, 0, 0, 0, 0};
            *(bf16x8*)(XT + n * 57344 + pp * 128 + c8) = z;
            continue;
        }
        e -= 16384;
        {   // Y0T lower-halo rows 0..63 -> zero
            int n = e >> 10, j = e & 1023;
            bf16x8 z = {0, 0, 0, 0, 0, 0, 0, 0};
            *(bf16x8*)(Y0T + n * 65536 + j * 8) = z;
        }
    }
}

// ---------- K1: fused stats (pool+pconv+BN/relu+tpool+alpha), one block per b ----------
__global__ __launch_bounds__(256) void k_stats(const float* __restrict__ x5,
        const float* __restrict__ pw, const float* __restrict__ pb,
        const float* __restrict__ g, const float* __restrict__ bb,
        const float* __restrict__ aw, float* __restrict__ alpha) {
    __shared__ float ppT[18][128];
    __shared__ float part[256];
    __shared__ float pooled[128];
    int b = blockIdx.x, t = threadIdx.x;
    if (t < 128) { ppT[0][t] = 0.f; ppT[17][t] = 0.f; }
    #pragma unroll
    for (int i = 0; i < 8; ++i) {
        int ct = t + 256 * i;
        const float* p = x5 + b * 49152 + ct * 24;
        float ssum = 0.f;
        #pragma unroll
        for (int j = 0; j < 6; ++j) {
            f32x4 v = *(const f32x4*)(p + 4 * j);
            ssum += v[0] + v[1] + v[2] + v[3];
        }
        ppT[1 + (ct & 15)][ct >> 4] = ssum * (1.f / 24.f);
    }
    __syncthreads();
    int o = t >> 1, th = (t & 1) * 8;
    float acc[8];
    float pbo = pb[o];
    #pragma unroll
    for (int i = 0; i < 8; ++i) acc[i] = pbo;
    for (int c4 = 0; c4 < 32; ++c4) {
        union { f32x4 v[3]; float f[12]; } u;
        u.v[0] = *(const f32x4*)(pw + o * 384 + c4 * 12);
        u.v[1] = *(const f32x4*)(pw + o * 384 + c4 * 12 + 4);
        u.v[2] = *(const f32x4*)(pw + o * 384 + c4 * 12 + 8);
        f32x4 pv[10];
        #pragma unroll
        for (int r = 0; r < 10; ++r) pv[r] = *(f32x4*)&ppT[th + r][c4 * 4];
        #pragma unroll
        for (int cc = 0; cc < 4; ++cc) {
            float a0 = u.f[cc * 3], a1 = u.f[cc * 3 + 1], a2 = u.f[cc * 3 + 2];
            #pragma unroll
            for (int i = 0; i < 8; ++i)
                acc[i] += a0 * pv[i][cc] + a1 * pv[i + 1][cc] + a2 * pv[i + 2][cc];
        }
    }
    float scale = g[o] * rsqrtf(1.f + 1e-5f);
    float beta = bb[o];
    float partial = 0.f;
    #pragma unroll
    for (int i = 0; i < 8; ++i) {
        float v = acc[i] * scale + beta;
        partial += v > 0.f ? v : 0.f;
    }
    part[t] = partial;
    __syncthreads();
    if (t < 128) pooled[t] = (part[2 * t] + part[2 * t + 1]) * (1.f / 16.f);
    __syncthreads();
    if (t < 128) {
        float a = 1.f;
        for (int c4 = 0; c4 < 32; ++c4) {
            f32x4 av = *(const f32x4*)(aw + t * 128 + c4 * 4);
            f32x4 pv4 = *(f32x4*)&pooled[c4 * 4];
            a += av[0] * pv4[0] + av[1] * pv4[1] + av[2] * pv4[2] + av[3] * pv4[3];
        }
        alpha[b * 128 + t] = a;
    }
}

// ---------- K2: conv-fwd GEMM, 32x32 tile, 768 one-wave blocks (3 waves/CU) ----------
__global__ __launch_bounds__(64) void k_gfwd(const unsigned short* __restrict__ XT,
        const unsigned short* __restrict__ Wp, const float* __restrict__ alpha,
        unsigned short* __restrict__ Y0T) {
    int bid = blockIdx.x;                 // 768 = 192 rm x 4 cn
    int rm = bid >> 2, cn = bid & 3;
    int n = rm / 12, p0 = (rm % 12) * 32;
    int o0 = cn * 32;
    int l = threadIdx.x;
    int sm = l & 15, skg = l >> 4;
    const unsigned short* XTn = XT + n * 57344;
    const unsigned short* WB = Wp + (o0 >> 4) * 512 + l * 8;
    f32x4 acc[2][2];
    #pragma unroll
    for (int mi = 0; mi < 2; ++mi)
        #pragma unroll
        for (int ni = 0; ni < 2; ++ni) acc[mi][ni] = (f32x4){0.f, 0.f, 0.f, 0.f};
    #pragma unroll
    for (int kt = 0; kt < 36; ++kt) {
        int a = kt >> 2;
        int off = (a / 3) * 24 + (a % 3);
        int kc = (kt & 3) * 32 + skg * 8;
        const unsigned short* ab = XTn + (p0 + sm + off) * 128 + kc;
        bf16x8 a0 = *(const bf16x8*)(ab);
        bf16x8 a1 = *(const bf16x8*)(ab + 2048);
        const unsigned short* wb = WB + kt * 4096;
        bf16x8 b0 = *(const bf16x8*)(wb);
        bf16x8 b1 = *(const bf16x8*)(wb + 512);
        acc[0][0] = mfma16(a0, b0, acc[0][0]);
        acc[0][1] = mfma16(a0, b1, acc[0][1]);
        acc[1][0] = mfma16(a1, b0, acc[1][0]);
        acc[1][1] = mfma16(a1, b1, acc[1][1]);
    }
    #pragma unroll
    for (int ni = 0; ni < 2; ++ni) {
        int o = o0 + ni * 16 + sm;
        float s = 0.f;
        #pragma unroll
        for (int bb2 = 0; bb2 < 16; ++bb2) { float a = alpha[bb2 * 128 + o]; s += a * a; }
        #pragma unroll
        for (int mi = 0; mi < 2; ++mi) {
            #pragma unroll
            for (int r = 0; r < 4; ++r) {
                int p = p0 + mi * 16 + skg * 4 + r;
                bool valid = ((p % 24) < cYW) && ((p / 24) < cYH);
                float v = valid ? acc[mi][ni][r] * s : 0.f;
                Y0T[n * 65536 + (64 + p) * 128 + o] = f2bf(v);
            }
        }
    }
}

// ---------- K3: conv-bwd GEMM 32x32 + residual RMW; emits XT (mode0) or xfM (mode1) ----------
__global__ __launch_bounds__(64) void k_gbwd(const unsigned short* __restrict__ Y0T,
        const unsigned short* __restrict__ Wpb, float* __restrict__ x5,
        unsigned short* __restrict__ xdst, int mode) {
    __shared__ unsigned short tr[32][36];
    int bid = blockIdx.x;                 // 768 = 192 rm x 4 cn
    int rm = bid >> 2, cn = bid & 3;
    int n = rm / 12, p0 = (rm % 12) * 32;
    int c0 = cn * 32;
    int l = threadIdx.x;
    int sm = l & 15, skg = l >> 4;
    const unsigned short* Yn = Y0T + n * 65536 + 64 * 128;
    const unsigned short* WB = Wpb + (c0 >> 4) * 512 + l * 8;
    f32x4 acc[2][2];
    #pragma unroll
    for (int mi = 0; mi < 2; ++mi)
        #pragma unroll
        for (int ni = 0; ni < 2; ++ni) acc[mi][ni] = (f32x4){0.f, 0.f, 0.f, 0.f};
    #pragma unroll
    for (int kt = 0; kt < 36; ++kt) {
        int a = kt >> 2;
        int off = (a / 3) * 24 + (a % 3);
        int kc = (kt & 3) * 32 + skg * 8;
        const unsigned short* ab = Yn + (p0 + sm - off) * 128 + kc;
        bf16x8 a0 = *(const bf16x8*)(ab);
        bf16x8 a1 = *(const bf16x8*)(ab + 2048);
        const unsigned short* wb = WB + kt * 4096;
        bf16x8 b0 = *(const bf16x8*)(wb);
        bf16x8 b1 = *(const bf16x8*)(wb + 512);
        acc[0][0] = mfma16(a0, b0, acc[0][0]);
        acc[0][1] = mfma16(a0, b1, acc[0][1]);
        acc[1][0] = mfma16(a1, b0, acc[1][0]);
        acc[1][1] = mfma16(a1, b1, acc[1][1]);
    }
    #pragma unroll
    for (int ni = 0; ni < 2; ++ni) {
        int cl = ni * 16 + sm;
        int c = c0 + cl;
        #pragma unroll
        for (int mi = 0; mi < 2; ++mi) {
            int pl = mi * 16 + skg * 4;
            float* dst = x5 + n * 49152 + c * 384 + p0 + pl;
            f32x4 ov = *(f32x4*)dst;
            #pragma unroll
            for (int r = 0; r < 4; ++r) {
                ov[r] += acc[mi][ni][r];
                tr[pl + r][cl] = f2bf(ov[r]);
            }
            *(f32x4*)dst = ov;
        }
    }
    __syncthreads();
    if (mode == 0) {
        // 32 rows x 32 c = 128 bf16x8 writes -> 2 passes
        #pragma unroll
        for (int pass = 0; pass < 2; ++pass) {
            int idx = pass * 64 + l;
            int row = idx >> 2, ch = idx & 3;
            *(bf16x8*)(xdst + n * 57344 + (p0 + row) * 128 + c0 + ch * 8) = *(bf16x8*)&tr[row][ch * 8];
        }
    } else {
        #pragma unroll
        for (int pass = 0; pass < 2; ++pass) {
            int idx = pass * 64 + l;
            int cl = idx >> 2, pl0 = (idx & 3) * 8;
            __attribute__((aligned(16))) unsigned short tmp[8];
            #pragma unroll
            for (int j2 = 0; j2 < 8; ++j2) tmp[j2] = tr[pl0 + j2][cl];
            *(bf16x8*)(xdst + n * 49152 + ((p0 >> 7) * 128 + c0 + cl) * 128 + (p0 & 127) + pl0) =
                *(bf16x8*)tmp;
        }
    }
}

// ---------- K4: fused head, one block per b: Zt in LDS, then out ----------
__global__ __launch_bounds__(256) void k_head(const unsigned short* __restrict__ xfM,
        const unsigned short* __restrict__ w2p, const unsigned short* __restrict__ w1p,
        const float* __restrict__ b1, const float* __restrict__ w2s,
        const float* __restrict__ b2, float* __restrict__ out) {
    __shared__ unsigned short ZtL[12288];   // [q 32][mh 384]
    int b = blockIdx.x, t = threadIdx.x;
    int w = t >> 6, l = t & 63;
    int sm = l & 15, skg = l >> 4;
    for (int zu = w; zu < 12; zu += 4) {
        int m0 = zu * 32;
        f32x4 acc[2][2];
        #pragma unroll
        for (int mi = 0; mi < 2; ++mi)
            #pragma unroll
            for (int ni = 0; ni < 2; ++ni) acc[mi][ni] = (f32x4){0.f, 0.f, 0.f, 0.f};
        #pragma unroll
        for (int kt = 0; kt < 4; ++kt) {
            int kc = kt * 32 + skg * 8;
            const unsigned short* ab = xfM + b * 49152 + (m0 + sm) * 128 + kc;
            bf16x8 a0 = *(const bf16x8*)(ab);
            bf16x8 a1 = *(const bf16x8*)(ab + 2048);
            bf16x8 b0 = *(const bf16x8*)(w2p + sm * 128 + kc);
            bf16x8 b1 = *(const bf16x8*)(w2p + (16 + sm) * 128 + kc);
            acc[0][0] = mfma16(a0, b0, acc[0][0]);
            acc[0][1] = mfma16(a0, b1, acc[0][1]);
            acc[1][0] = mfma16(a1, b0, acc[1][0]);
            acc[1][1] = mfma16(a1, b1, acc[1][1]);
        }
        #pragma unroll
        for (int mi = 0; mi < 2; ++mi)
            #pragma unroll
            for (int ni = 0; ni < 2; ++ni) {
                int q = ni * 16 + sm;
                int mh = m0 + mi * 16 + skg * 4;
                #pragma unroll
                for (int r = 0; r < 4; ++r)
                    ZtL[q * 384 + mh + r] = f2bf(acc[mi][ni][r]);
            }
    }
    __syncthreads();
    if (w < 3) {
        int p0 = w * 32;
        f32x4 acc[2][2];
        #pragma unroll
        for (int mi = 0; mi < 2; ++mi)
            #pragma unroll
            for (int ni = 0; ni < 2; ++ni) acc[mi][ni] = (f32x4){0.f, 0.f, 0.f, 0.f};
        #pragma unroll
        for (int kt = 0; kt < 12; ++kt) {
            int kc = kt * 32 + skg * 8;
            const unsigned short* ab = w1p + (p0 + sm) * 384 + kc;
            bf16x8 a0 = *(const bf16x8*)(ab);
            bf16x8 a1 = *(const bf16x8*)(ab + 16 * 384);
            bf16x8 b0 = *(const bf16x8*)(&ZtL[sm * 384 + kc]);
            bf16x8 b1v = *(const bf16x8*)(&ZtL[(16 + sm) * 384 + kc]);
            acc[0][0] = mfma16(a0, b0, acc[0][0]);
            acc[0][1] = mfma16(a0, b1v, acc[0][1]);
            acc[1][0] = mfma16(a1, b0, acc[1][0]);
            acc[1][1] = mfma16(a1, b1v, acc[1][1]);
        }
        #pragma unroll
        for (int ni = 0; ni < 2; ++ni) {
            int q = ni * 16 + sm;
            if (q < 21) {
                float wsq = w2s[q], bq = b2[q];
                #pragma unroll
                for (int mi = 0; mi < 2; ++mi) {
                    #pragma unroll
                    for (int r = 0; r < 4; ++r) {
                        int p = p0 + mi * 16 + skg * 4 + r;
                        out[b * 2016 + p * 21 + q] = acc[mi][ni][r] + b1[p] * wsq + bq;
                    }
                }
            }
        }
    }
}

extern "C" void kernel_launch(void* const* d_in, const int* in_sizes, int n_in,
                              void* d_out, int out_size, void* d_ws, size_t ws_size,
                              hipStream_t stream) {
    const float* x       = (const float*)d_in[0];
    const float* token_w = (const float*)d_in[1];
    const float* patch_w = (const float*)d_in[2];
    const float* patch_b = (const float*)d_in[3];
    const float* Wi      = (const float*)d_in[4];
    const float* pconv_w = (const float*)d_in[5];
    const float* pconv_b = (const float*)d_in[6];
    const float* bn_g    = (const float*)d_in[7];
    const float* bn_b    = (const float*)d_in[8];
    const float* aconv_w = (const float*)d_in[9];
    const float* fc1_w   = (const float*)d_in[10];
    const float* fc1_b   = (const float*)d_in[11];
    const float* fc2_w   = (const float*)d_in[12];
    const float* fc2_b   = (const float*)d_in[13];
    float* out = (float*)d_out;

    // ---- workspace layout (float offsets) ----
    float* ws    = (float*)d_ws;
    float* x5    = ws;                                        // 786432 f
    float* alpha = ws + 786432;                               // 2048 f
    unsigned short* Wp  = (unsigned short*)(ws + 788480);     // 589824 ush
    unsigned short* w1p = (unsigned short*)(ws + 1083392);    // 36864 ush
    unsigned short* w2p = (unsigned short*)(ws + 1101824);    // 4096 ush
    float* w2s   = ws + 1103872;                              // 32 f
    unsigned short* XT  = (unsigned short*)(ws + 1103904);    // 917504 ush (alias xfM)
    unsigned short* Y0T = (unsigned short*)(ws + 1562656);    // 1048576 ush (alias Zt)

    k_initep<<<768, 256, 0, stream>>>(x, token_w, patch_w, patch_b, Wi, fc1_w, fc2_w,
                                      x5, XT, Wp, w1p, w2p, w2s, Y0T);
    // layer 0
    k_stats<<<16, 256, 0, stream>>>(x5, pconv_w, pconv_b, bn_g, bn_b, aconv_w, alpha);
    k_gfwd<<<768, 64, 0, stream>>>(XT, Wp, alpha, Y0T);
    k_gbwd<<<768, 64, 0, stream>>>(Y0T, Wp + 147456, x5, XT, 0);
    // layer 1
    k_stats<<<16, 256, 0, stream>>>(x5, pconv_w + 49152, pconv_b + 128, bn_g + 128,
                                    bn_b + 128, aconv_w + 16384, alpha);
    k_gfwd<<<768, 64, 0, stream>>>(XT, Wp + 294912, alpha, Y0T);
    k_gbwd<<<768, 64, 0, stream>>>(Y0T, Wp + 442368, x5, XT /*xfM*/, 1);
    // head
    k_head<<<16, 256, 0, stream>>>(XT /*xfM*/, w2p, w1p, fc1_b, w2s, fc2_b, out);
}